// Round 1
// baseline (861.389 us; speedup 1.0000x reference)
//
#include <hip/hip_runtime.h>

// Problem constants (from reference setup_inputs)
constexpr int NN = 100000;   // nodes
constexpr int NE = 1250000;  // edges
constexpr int KDIM = 128;    // IN_DIM
constexpr int HID = 64;

// ---------------- degree / norm ----------------

__global__ void k_zero_deg(int* __restrict__ deg) {
    int i = blockIdx.x * blockDim.x + threadIdx.x;
    if (i < NN) deg[i] = 0;
}

__global__ void k_count_deg(const int* __restrict__ dst, int* __restrict__ deg) {
    int i = blockIdx.x * blockDim.x + threadIdx.x;
    if (i < NE) atomicAdd(&deg[dst[i]], 1);
}

__global__ void k_dinv(const int* __restrict__ deg, float* __restrict__ dinv) {
    int i = blockIdx.x * blockDim.x + threadIdx.x;
    if (i < NN) dinv[i] = rsqrtf((float)(deg[i] + 1));  // +1 self loop
}

// ---------------- node-feature GEMM: out[N,64] = act(x)[N,K] @ W[K,64] ----------------
// Block = 256 threads = 64 cols x 4 row-groups; 16 rows per block (4 rows/thread).
// W staged in LDS (K*64*4B), x rows staged in LDS.

template <int K, bool RELU_IN>
__global__ __launch_bounds__(256) void k_gemm(const float* __restrict__ x,
                                              const float* __restrict__ W,
                                              float* __restrict__ out) {
    __shared__ float Ws[K * HID];
    __shared__ float xs[16 * K];
    for (int i = threadIdx.x; i < K * HID; i += 256) Ws[i] = W[i];
    const int row0 = blockIdx.x * 16;
    for (int i = threadIdx.x; i < 16 * K; i += 256) {
        int r = row0 + i / K;
        float v = (r < NN) ? x[r * K + (i % K)] : 0.0f;
        if (RELU_IN) v = fmaxf(v, 0.0f);
        xs[i] = v;
    }
    __syncthreads();
    const int col = threadIdx.x & 63;
    const int rg  = threadIdx.x >> 6;  // 0..3
    float acc[4] = {0.f, 0.f, 0.f, 0.f};
    for (int k = 0; k < K; ++k) {
        float w = Ws[k * HID + col];        // stride-1 across lanes: conflict-free
#pragma unroll
        for (int m = 0; m < 4; ++m)
            acc[m] += xs[(rg + 4 * m) * K + k] * w;  // broadcast across 64 cols
    }
#pragma unroll
    for (int m = 0; m < 4; ++m) {
        int row = row0 + rg + 4 * m;
        if (row < NN) out[row * HID + col] = acc[m];
    }
}

// ---------------- init out with self-loop term + bias ----------------
// out[v][j] = dinv[v]^2 * h[v][j] + b[j]

__global__ void k_init(const float* __restrict__ h, const float* __restrict__ dinv,
                       const float* __restrict__ b, float* __restrict__ out) {
    int i = blockIdx.x * blockDim.x + threadIdx.x;
    if (i >= NN * HID) return;
    int v = i >> 6;
    float di = dinv[v];
    out[i] = di * di * h[i] + b[i & 63];
}

// ---------------- edge aggregation ----------------
// One wave (64 lanes) per edge: lane j handles feature j.
// src/dst/dinv loads are wave-uniform (broadcast); h gather + atomic are
// coalesced 256B wave transactions.

__global__ void k_edge(const int* __restrict__ src, const int* __restrict__ dst,
                       const float* __restrict__ dinv, const float* __restrict__ h,
                       float* __restrict__ out) {
    int i = blockIdx.x * blockDim.x + threadIdx.x;
    if (i >= NE * HID) return;  // 80,000,000 < 2^31
    int e = i >> 6, j = i & 63;
    int s = src[e], d = dst[e];
    float nrm = dinv[s] * dinv[d];
    atomicAdd(&out[d * HID + j], nrm * h[s * HID + j]);
}

// ---------------- launch ----------------

extern "C" void kernel_launch(void* const* d_in, const int* in_sizes, int n_in,
                              void* d_out, int out_size, void* d_ws, size_t ws_size,
                              hipStream_t stream) {
    const float* x  = (const float*)d_in[0];
    const int*   ei = (const int*)d_in[1];
    const float* W1 = (const float*)d_in[2];
    const float* b1 = (const float*)d_in[3];
    const float* W2 = (const float*)d_in[4];
    const float* b2 = (const float*)d_in[5];
    float* out = (float*)d_out;
    (void)in_sizes; (void)n_in; (void)out_size; (void)ws_size;

    const int* src = ei;
    const int* dst = ei + NE;

    // Workspace layout (bytes): deg 400000 | dinv 400000 | h1 25.6MB | agg1 25.6MB
    char* ws = (char*)d_ws;
    int*   deg  = (int*)(ws);
    float* dinv = (float*)(ws + 400000);
    float* h1   = (float*)(ws + 800000);
    float* agg1 = (float*)(ws + 26400000);
    float* t    = h1;  // reuse h1's slot for layer-2 XW (stream-ordered, h1 dead by then)

    const int B = 256;

    // degrees + normalization
    k_zero_deg<<<(NN + B - 1) / B, B, 0, stream>>>(deg);
    k_count_deg<<<(NE + B - 1) / B, B, 0, stream>>>(dst, deg);
    k_dinv<<<(NN + B - 1) / B, B, 0, stream>>>(deg, dinv);

    // layer 1: h1 = x @ W1 ; agg1 = Dinv(A+I)Dinv h1 + b1
    k_gemm<KDIM, false><<<(NN + 15) / 16, B, 0, stream>>>(x, W1, h1);
    k_init<<<(NN * HID + B - 1) / B, B, 0, stream>>>(h1, dinv, b1, agg1);
    k_edge<<<(NE * HID + B - 1) / B, B, 0, stream>>>(src, dst, dinv, h1, agg1);

    // layer 2: t = relu(agg1) @ W2 ; out = Dinv(A+I)Dinv t + b2
    k_gemm<HID, true><<<(NN + 15) / 16, B, 0, stream>>>(agg1, W2, t);
    k_init<<<(NN * HID + B - 1) / B, B, 0, stream>>>(t, dinv, b2, out);
    k_edge<<<(NE * HID + B - 1) / B, B, 0, stream>>>(src, dst, dinv, t, out);
}

// Round 2
// 462.465 us; speedup vs baseline: 1.8626x; 1.8626x over previous
//
#include <hip/hip_runtime.h>

constexpr int NN = 100000;   // nodes
constexpr int NE = 1250000;  // edges
constexpr int KDIM = 128;    // IN_DIM
constexpr int HID = 64;

constexpr int SCAN_ITEMS  = 1024;                                  // per scan block
constexpr int SCAN_BLOCKS = (NN + SCAN_ITEMS - 1) / SCAN_ITEMS;    // 98

// ---------------- degree / norm ----------------

__global__ void k_zero_deg(int* __restrict__ deg) {
    int i = blockIdx.x * blockDim.x + threadIdx.x;
    if (i < NN) deg[i] = 0;
}

__global__ void k_count_deg(const int* __restrict__ dst, int* __restrict__ deg) {
    int i = blockIdx.x * blockDim.x + threadIdx.x;
    if (i < NE) atomicAdd(&deg[dst[i]], 1);
}

__global__ void k_dinv(const int* __restrict__ deg, float* __restrict__ dinv) {
    int i = blockIdx.x * blockDim.x + threadIdx.x;
    if (i < NN) dinv[i] = rsqrtf((float)(deg[i] + 1));  // +1 self loop
}

// ---------------- 3-kernel exclusive scan of deg -> row_start ----------------

__global__ __launch_bounds__(256) void k_scan1(const int* __restrict__ deg,
                                               int* __restrict__ row_start,
                                               int* __restrict__ blocksum) {
    __shared__ int sh[256];
    const int t = threadIdx.x;
    const int base = blockIdx.x * SCAN_ITEMS + t * 4;
    int v[4], s = 0;
#pragma unroll
    for (int j = 0; j < 4; ++j) { v[j] = (base + j < NN) ? deg[base + j] : 0; s += v[j]; }
    sh[t] = s;
    __syncthreads();
    int val = s;
    for (int off = 1; off < 256; off <<= 1) {
        int add = (t >= off) ? sh[t - off] : 0;
        __syncthreads();
        val += add;
        sh[t] = val;
        __syncthreads();
    }
    int run = val - s;  // exclusive prefix of this thread's chunk
#pragma unroll
    for (int j = 0; j < 4; ++j) {
        if (base + j < NN) row_start[base + j] = run;
        run += v[j];
    }
    if (t == 255) blocksum[blockIdx.x] = val;
}

__global__ __launch_bounds__(128) void k_scan2(const int* __restrict__ blocksum,
                                               int* __restrict__ blockpref) {
    __shared__ int sh[128];
    const int t = threadIdx.x;
    int s = (t < SCAN_BLOCKS) ? blocksum[t] : 0;
    sh[t] = s;
    __syncthreads();
    int val = s;
    for (int off = 1; off < 128; off <<= 1) {
        int add = (t >= off) ? sh[t - off] : 0;
        __syncthreads();
        val += add;
        sh[t] = val;
        __syncthreads();
    }
    if (t < SCAN_BLOCKS) blockpref[t] = val - s;  // exclusive
}

__global__ void k_scan3(int* __restrict__ row_start, const int* __restrict__ blockpref,
                        int* __restrict__ cursor) {
    int i = blockIdx.x * blockDim.x + threadIdx.x;
    if (i >= NN) return;
    int v = row_start[i] + blockpref[i >> 10];
    row_start[i] = v;
    cursor[i] = v;
}

// ---------------- scatter edges into dst-sorted order ----------------
// pack[p] = (src, dinv[src]) for edges grouped by dst

__global__ void k_scatter(const int* __restrict__ src, const int* __restrict__ dst,
                          const float* __restrict__ dinv, int* __restrict__ cursor,
                          int2* __restrict__ pack) {
    int e = blockIdx.x * blockDim.x + threadIdx.x;
    if (e >= NE) return;
    int d = dst[e], s = src[e];
    int p = atomicAdd(&cursor[d], 1);
    pack[p] = make_int2(s, __float_as_int(dinv[s]));
}

// ---------------- node-feature GEMM: out[N,64] = act(x)[N,K] @ W[K,64] ----------------
// 128 threads/block, C-tile 128x64, 8x8 per thread. W fully LDS-resident,
// A-tile staged transposed (As[kk][row]) so inner loop = 4x ds_read_b128 / 64 FMA.

template <int K, bool RELU_IN>
__global__ __launch_bounds__(128) void k_gemm(const float* __restrict__ x,
                                              const float* __restrict__ W,
                                              float* __restrict__ out) {
    __shared__ float Bs[K * HID];     // 32 KB (K=128) / 16 KB (K=64)
    __shared__ float As[16][128];     // 8 KB
    const int t = threadIdx.x;
    for (int i = t; i < K * HID; i += 128) Bs[i] = W[i];

    const int row0 = blockIdx.x * 128;
    const int ty = t >> 3;   // 0..15 -> 8 rows each
    const int tx = t & 7;    // 0..7  -> 8 cols each
    float acc[8][8] = {};

    for (int k0 = 0; k0 < K; k0 += 16) {
        __syncthreads();  // As reads from prev iter done (also orders Bs stage on iter 0)
        for (int i = t; i < 512; i += 128) {
            int r = i >> 2, q = i & 3;
            int row = row0 + r;
            float4 xv = make_float4(0.f, 0.f, 0.f, 0.f);
            if (row < NN) xv = *(const float4*)(x + row * K + k0 + q * 4);
            if (RELU_IN) {
                xv.x = fmaxf(xv.x, 0.f); xv.y = fmaxf(xv.y, 0.f);
                xv.z = fmaxf(xv.z, 0.f); xv.w = fmaxf(xv.w, 0.f);
            }
            As[q * 4 + 0][r] = xv.x; As[q * 4 + 1][r] = xv.y;
            As[q * 4 + 2][r] = xv.z; As[q * 4 + 3][r] = xv.w;
        }
        __syncthreads();
#pragma unroll
        for (int kk = 0; kk < 16; ++kk) {
            float4 a0 = *(const float4*)&As[kk][ty * 8];
            float4 a1 = *(const float4*)&As[kk][ty * 8 + 4];
            float4 b0 = *(const float4*)&Bs[(k0 + kk) * HID + tx * 8];
            float4 b1 = *(const float4*)&Bs[(k0 + kk) * HID + tx * 8 + 4];
            float a[8] = {a0.x, a0.y, a0.z, a0.w, a1.x, a1.y, a1.z, a1.w};
            float b[8] = {b0.x, b0.y, b0.z, b0.w, b1.x, b1.y, b1.z, b1.w};
#pragma unroll
            for (int m = 0; m < 8; ++m)
#pragma unroll
                for (int n = 0; n < 8; ++n) acc[m][n] += a[m] * b[n];
        }
    }

#pragma unroll
    for (int m = 0; m < 8; ++m) {
        int row = row0 + ty * 8 + m;
        if (row < NN) {
            float4 o0 = make_float4(acc[m][0], acc[m][1], acc[m][2], acc[m][3]);
            float4 o1 = make_float4(acc[m][4], acc[m][5], acc[m][6], acc[m][7]);
            *(float4*)(out + row * HID + tx * 8)     = o0;
            *(float4*)(out + row * HID + tx * 8 + 4) = o1;
        }
    }
}

// ---------------- CSR aggregation: one wave per node ----------------
// out[v][j] = dinv[v] * ( sum_{s in N(v)} dinv[s]*h[s][j] + dinv[v]*h[v][j] ) + b[j]

__global__ __launch_bounds__(256) void k_agg(const int* __restrict__ row_start,
                                             const int* __restrict__ deg,
                                             const int2* __restrict__ pack,
                                             const float* __restrict__ dinv,
                                             const float* __restrict__ h,
                                             const float* __restrict__ b,
                                             float* __restrict__ out) {
    const int v = blockIdx.x * 4 + (threadIdx.x >> 6);
    const int j = threadIdx.x & 63;
    if (v >= NN) return;
    const float dv = dinv[v];
    float acc = dv * h[v * HID + j];  // self-loop (gets another *dv at the end)
    const int beg = row_start[v];
    const int cnt = deg[v];
    int2 pre = make_int2(0, 0);
    if (j < cnt) pre = pack[beg + j];  // coalesced cooperative preload
    const int n0 = cnt < 64 ? cnt : 64;
    for (int k = 0; k < n0; ++k) {
        int s   = __shfl(pre.x, k);
        float a = __int_as_float(__shfl(pre.y, k));
        acc += a * h[s * HID + j];     // coalesced 256B wave gather
    }
    for (int k = 64; k < cnt; ++k) {   // rare (deg > 64)
        int2 p = pack[beg + k];
        acc += __int_as_float(p.y) * h[p.x * HID + j];
    }
    out[v * HID + j] = dv * acc + b[j];
}

// ---------------- launch ----------------

extern "C" void kernel_launch(void* const* d_in, const int* in_sizes, int n_in,
                              void* d_out, int out_size, void* d_ws, size_t ws_size,
                              hipStream_t stream) {
    const float* x  = (const float*)d_in[0];
    const int*   ei = (const int*)d_in[1];
    const float* W1 = (const float*)d_in[2];
    const float* b1 = (const float*)d_in[3];
    const float* W2 = (const float*)d_in[4];
    const float* b2 = (const float*)d_in[5];
    float* out = (float*)d_out;
    (void)in_sizes; (void)n_in; (void)out_size; (void)ws_size;

    const int* src = ei;
    const int* dst = ei + NE;

    // Workspace layout (ws >= 52MB proven in R1; this uses ~38MB)
    char* ws = (char*)d_ws;
    int*   deg       = (int*)(ws + 0x000000);   // 512 KB slot
    float* dinv      = (float*)(ws + 0x080000); // 512 KB
    int*   row_start = (int*)(ws + 0x100000);   // 512 KB
    int*   cursor    = (int*)(ws + 0x180000);   // 512 KB
    int*   blocksum  = (int*)(ws + 0x200000);   // 4 KB
    int*   blockpref = (int*)(ws + 0x201000);   // 4 KB
    int2*  pack      = (int2*)(ws + 0x210000);  // 10 MB
    float* h1        = (float*)(ws + 0xC10000); // 25.6 MB
    float* agg1 = out;  // layer-1 agg result lives in d_out temporarily
    float* t    = h1;   // layer-2 XW reuses h1's slot (h1 dead by then)

    const int B = 256;
    const int gN = (NN + B - 1) / B;
    const int gE = (NE + B - 1) / B;

    // CSR build + normalization
    k_zero_deg<<<gN, B, 0, stream>>>(deg);
    k_count_deg<<<gE, B, 0, stream>>>(dst, deg);
    k_scan1<<<SCAN_BLOCKS, 256, 0, stream>>>(deg, row_start, blocksum);
    k_scan2<<<1, 128, 0, stream>>>(blocksum, blockpref);
    k_scan3<<<gN, B, 0, stream>>>(row_start, blockpref, cursor);
    k_dinv<<<gN, B, 0, stream>>>(deg, dinv);
    k_scatter<<<gE, B, 0, stream>>>(src, dst, dinv, cursor, pack);

    // layer 1: h1 = x @ W1 ; agg1 = Dinv(A+I)Dinv h1 + b1
    k_gemm<KDIM, false><<<(NN + 127) / 128, 128, 0, stream>>>(x, W1, h1);
    k_agg<<<(NN + 3) / 4, 256, 0, stream>>>(row_start, deg, pack, dinv, h1, b1, agg1);

    // layer 2: t = relu(agg1) @ W2 ; out = Dinv(A+I)Dinv t + b2
    k_gemm<HID, true><<<(NN + 127) / 128, 128, 0, stream>>>(agg1, W2, t);
    k_agg<<<(NN + 3) / 4, 256, 0, stream>>>(row_start, deg, pack, dinv, t, b2, out);
}